// Round 7
// baseline (518.056 us; speedup 1.0000x reference)
//
#include <hip/hip_runtime.h>
#include <math.h>

#define NN 100000
#define EE 1600000
#define RSIZE 12500     // nodes per dst-range (8 ranges)
#define SEG 204800      // per-range segment capacity in tmp arrays

typedef _Float16 f16;
typedef __attribute__((ext_vector_type(2))) _Float16 f16x2;
typedef __attribute__((ext_vector_type(8))) _Float16 f16x8;
typedef __attribute__((ext_vector_type(4))) float f32x4;
typedef unsigned int u32;

__device__ __forceinline__ float frelu(float v){ return v > 0.f ? v : 0.f; }

__device__ __forceinline__ f32x4 mfma16(f16x8 a, f16x8 b, f32x4 c){
    return __builtin_amdgcn_mfma_f32_16x16x32_f16(a, b, c, 0, 0, 0);
}

// ---------------------------------------------------------------------------
// CSR build, two-pass partition:
//  A) partition_edges: single sequential read of {src,dst,ea}; LDS 8-bin
//     histogram + one global atomic per block per bin; compacted writes into
//     per-range segments (sequential).
//  B) count_part / fill_from_parts: stream compacted segment; scatter into
//     1.6MB pairs window + 50KB offsets window, XCD-affine (blockIdx&7) ->
//     L2-local atomics and write-combining (kills R5's read & write amp).
// ---------------------------------------------------------------------------
__global__ __launch_bounds__(256) void partition_edges(const int* __restrict__ src,
                                                       const int* __restrict__ dst,
                                                       const float* __restrict__ ea,
                                                       int* __restrict__ cursor,
                                                       int2* __restrict__ tmp_pairs,
                                                       int* __restrict__ tmp_dst)
{
    __shared__ int lcount[8];
    __shared__ int lbase[8];
    const int t = threadIdx.x;
    const int ebase = blockIdx.x * 6400;      // 250 blocks exact: 250*6400 = EE
    if (t < 8) lcount[t] = 0;
    __syncthreads();
    int rs[25];
    #pragma unroll
    for (int i = 0; i < 25; i++) {
        int e = ebase + i * 256 + t;
        int r = dst[e] / RSIZE;
        rs[i] = r;
        atomicAdd(&lcount[r], 1);
    }
    __syncthreads();
    if (t < 8) lbase[t] = atomicAdd(&cursor[t], lcount[t]);
    __syncthreads();
    if (t < 8) lcount[t] = 0;                 // reuse as rank counters
    __syncthreads();
    #pragma unroll
    for (int i = 0; i < 25; i++) {
        int e = ebase + i * 256 + t;
        int r = rs[i];
        int rank = atomicAdd(&lcount[r], 1);
        int p = r * SEG + lbase[r] + rank;
        tmp_pairs[p] = make_int2(src[e], __float_as_int(ea[e]));
        tmp_dst[p]   = dst[e];
    }
}

__global__ __launch_bounds__(256) void count_part(const int* __restrict__ tmp_dst,
                                                  const int* __restrict__ cursor,
                                                  int* __restrict__ counts)
{
    const int r = blockIdx.x & 7;             // XCD-affine range
    const int cb = blockIdx.x >> 3;           // 64 blocks per range
    const int n = cursor[r];
    const int* seg = tmp_dst + r * SEG;
    for (int i = cb * 256 + threadIdx.x; i < n; i += 64 * 256)
        atomicAdd(&counts[seg[i]], 1);
}

__global__ __launch_bounds__(256) void scan_blocks(const int* __restrict__ counts,
                                                   int* __restrict__ offsets,
                                                   int* __restrict__ bsums)
{
    __shared__ int lds[256];
    const int t = threadIdx.x, b = blockIdx.x;
    const int base = b * 1024 + t * 4;
    int v[4];
    #pragma unroll
    for (int i = 0; i < 4; i++) { int idx = base + i; v[i] = (idx < NN) ? counts[idx] : 0; }
    int s = v[0] + v[1] + v[2] + v[3];
    lds[t] = s;
    __syncthreads();
    for (int off = 1; off < 256; off <<= 1) {
        int y = (t >= off) ? lds[t - off] : 0;
        __syncthreads();
        lds[t] += y;
        __syncthreads();
    }
    int run = (t > 0) ? lds[t - 1] : 0;
    if (t == 255) bsums[b] = lds[255];
    #pragma unroll
    for (int i = 0; i < 4; i++) { int idx = base + i; if (idx < NN) offsets[idx] = run; run += v[i]; }
}

__global__ __launch_bounds__(128) void scan_sums(int* __restrict__ bsums)
{
    __shared__ int lds[128];
    const int t = threadIdx.x;
    lds[t] = (t < 98) ? bsums[t] : 0;
    __syncthreads();
    for (int off = 1; off < 128; off <<= 1) {
        int y = (t >= off) ? lds[t - off] : 0;
        __syncthreads();
        lds[t] += y;
        __syncthreads();
    }
    if (t < 98) bsums[t] = (t > 0) ? lds[t - 1] : 0;
}

__global__ __launch_bounds__(256) void scan_add(int* __restrict__ offsets,
                                                const int* __restrict__ bsums)
{
    const int b = blockIdx.x;
    const int add = bsums[b];
    const int base = b * 1024 + threadIdx.x * 4;
    #pragma unroll
    for (int i = 0; i < 4; i++) { int idx = base + i; if (idx < NN) offsets[idx] += add; }
}

__global__ __launch_bounds__(256) void fill_from_parts(const int2* __restrict__ tmp_pairs,
                                                       const int* __restrict__ tmp_dst,
                                                       const int* __restrict__ cursor,
                                                       int* __restrict__ offsets,
                                                       int2* __restrict__ pairs)
{
    const int r = blockIdx.x & 7;             // XCD-affine range
    const int cb = blockIdx.x >> 3;
    const int n = cursor[r];
    const int* segd = tmp_dst + r * SEG;
    const int2* segp = tmp_pairs + r * SEG;
    for (int i = cb * 256 + threadIdx.x; i < n; i += 64 * 256) {
        int d = segd[i];
        int p = atomicAdd(&offsets[d], 1);
        pairs[p] = segp[i];
    }
}

// ---------------------------------------------------------------------------
// Aggregation: quarter-wave (16 lanes x 16B) per node. 4 nodes per wave,
// 1KB of gather data in flight per wave-instruction, v_fma_mix accumulate.
// ---------------------------------------------------------------------------
__global__ __launch_bounds__(256) void agg_q(const f16* __restrict__ h,
                                             const int2* __restrict__ pairs,
                                             const int* __restrict__ offsets,
                                             const int* __restrict__ counts,
                                             f16* __restrict__ out)
{
    const int gt   = blockIdx.x * 256 + threadIdx.x;   // grid exact: 6250*256
    const int node = gt >> 4;                          // 100000 nodes
    const int ch   = gt & 15;                          // 16B chunk within row
    const int end  = offsets[node];
    int i = end - counts[node];
    float acc[8];
    #pragma unroll
    for (int j = 0; j < 8; j++) acc[j] = 0.f;
    const uint4* __restrict__ h16 = (const uint4*)h;   // 16 chunks per row
    for (; i + 2 <= end; i += 2) {
        int2 p0 = pairs[i], p1 = pairs[i + 1];
        uint4 r0 = h16[(size_t)p0.x * 16 + ch];
        uint4 r1 = h16[(size_t)p1.x * 16 + ch];
        float w0 = __int_as_float(p0.y), w1 = __int_as_float(p1.y);
        const f16* e0 = (const f16*)&r0;
        const f16* e1 = (const f16*)&r1;
        #pragma unroll
        for (int j = 0; j < 8; j++) acc[j] = fmaf(w0, (float)e0[j], acc[j]);
        #pragma unroll
        for (int j = 0; j < 8; j++) acc[j] = fmaf(w1, (float)e1[j], acc[j]);
    }
    if (i < end) {
        int2 p0 = pairs[i];
        uint4 r0 = h16[(size_t)p0.x * 16 + ch];
        float w0 = __int_as_float(p0.y);
        const f16* e0 = (const f16*)&r0;
        #pragma unroll
        for (int j = 0; j < 8; j++) acc[j] = fmaf(w0, (float)e0[j], acc[j]);
    }
    union { f16 hh[8]; uint4 u; } cv;
    #pragma unroll
    for (int j = 0; j < 8; j++) cv.hh[j] = (f16)acc[j];
    ((uint4*)out)[(size_t)node * 16 + ch] = cv.u;
}

// ---------------------------------------------------------------------------
// Weight packing into MFMA fragment order (fp16).
// pack[(kk*CT+ct)*64 + lane][j] = W[kk*32 + (lane>>4)*8 + j][ct*16 + (lane&15)]
// ---------------------------------------------------------------------------
__global__ __launch_bounds__(256) void prep_pack(const float* __restrict__ W1,
                                                 const float* __restrict__ W2,
                                                 const float* __restrict__ Wrel1,
                                                 const float* __restrict__ Wroot1,
                                                 const float* __restrict__ Wrel2,
                                                 const float* __restrict__ Wroot2,
                                                 const float* __restrict__ Wd1,
                                                 const float* __restrict__ Wd2,
                                                 f16* __restrict__ pack)
{
    int t = blockIdx.x * 256 + threadIdx.x;   // grid exact: 151552/256 = 592
    float v;
    if (t < 32768) {                          // enc1: W1 [256,128], CT=8
        int l = t;
        int j = l & 7, lane = (l >> 3) & 63, ct = (l >> 9) & 7, kk = l >> 12;
        int k = kk * 32 + ((lane >> 4) << 3) + j, c = (ct << 4) + (lane & 15);
        v = W1[k * 128 + c];
    } else if (t < 49152) {                   // enc2: W2 [128,128], CT=8
        int l = t - 32768;
        int j = l & 7, lane = (l >> 3) & 63, ct = (l >> 9) & 7, kk = l >> 12;
        int k = kk * 32 + ((lane >> 4) << 3) + j, c = (ct << 4) + (lane & 15);
        v = W2[k * 128 + c];
    } else if (t < 81920) {                   // conv1: [Wrel1;Wroot1] K=256, CT=8
        int l = t - 49152;
        int j = l & 7, lane = (l >> 3) & 63, ct = (l >> 9) & 7, kk = l >> 12;
        int k = kk * 32 + ((lane >> 4) << 3) + j, c = (ct << 4) + (lane & 15);
        v = (k < 128) ? Wrel1[k * 128 + c] : Wroot1[(k - 128) * 128 + c];
    } else if (t < 114688) {                  // conv2
        int l = t - 81920;
        int j = l & 7, lane = (l >> 3) & 63, ct = (l >> 9) & 7, kk = l >> 12;
        int k = kk * 32 + ((lane >> 4) << 3) + j, c = (ct << 4) + (lane & 15);
        v = (k < 128) ? Wrel2[k * 128 + c] : Wroot2[(k - 128) * 128 + c];
    } else if (t < 118784) {                  // dec1: Wd1 [32,128], CT=8, kk=0
        int l = t - 114688;
        int j = l & 7, lane = (l >> 3) & 63, ct = (l >> 9) & 7;
        int k = ((lane >> 4) << 3) + j, c = (ct << 4) + (lane & 15);
        v = Wd1[k * 128 + c];
    } else {                                  // dec2: Wd2 [128,256], CT=16
        int l = t - 118784;
        int j = l & 7, lane = (l >> 3) & 63, ct = (l >> 9) & 15, kk = l >> 13;
        int k = kk * 32 + ((lane >> 4) << 3) + j, c = (ct << 4) + (lane & 15);
        v = Wd2[k * 256 + c];
    }
    pack[t] = (f16)v;
}

// ---------------------------------------------------------------------------
// MFMA GEMM building blocks. 64 nodes/block, 4 waves, wave = 16 nodes.
// ---------------------------------------------------------------------------
template<int C>
__device__ __forceinline__ void stage_tile(const float* __restrict__ src, int nbase,
                                           f16* lds, int ldr, int colofs)
{
    const int t = threadIdx.x;
    #pragma unroll
    for (int i = 0; i < (64 * C / 4) / 256; i++) {
        int elem = t + i * 256;
        int row = elem / (C / 4);
        int c4  = elem % (C / 4);
        int srow = nbase + row; if (srow >= NN) srow = NN - 1;
        float4 v = *(const float4*)(src + (size_t)srow * C + c4 * 4);
        union { f16 h[4]; uint2 u; } cv;
        cv.h[0] = (f16)v.x; cv.h[1] = (f16)v.y; cv.h[2] = (f16)v.z; cv.h[3] = (f16)v.w;
        *(uint2*)&lds[row * ldr + colofs + c4 * 4] = cv.u;
    }
}

template<int C>
__device__ __forceinline__ void stage_tile_f16(const f16* __restrict__ src, int nbase,
                                               f16* lds, int ldr, int colofs)
{
    const int t = threadIdx.x;
    #pragma unroll
    for (int i = 0; i < (64 * C / 4) / 256; i++) {
        int elem = t + i * 256;
        int row = elem / (C / 4);
        int c4  = elem % (C / 4);
        int srow = nbase + row; if (srow >= NN) srow = NN - 1;
        uint2 v = *(const uint2*)(src + (size_t)srow * C + c4 * 4);
        *(uint2*)&lds[row * ldr + colofs + c4 * 4] = v;
    }
}

template<int K, int CT>
__device__ __forceinline__ void wave_gemm(const f16* lds, int ldr,
                                          const f16x8* __restrict__ wp, f32x4 acc[CT])
{
    const int lane = threadIdx.x & 63;
    const int wrow = (threadIdx.x >> 6) * 16;
    const int arow = wrow + (lane & 15);
    const int kofs = (lane >> 4) << 3;
    #pragma unroll
    for (int kk = 0; kk < K / 32; kk++) {
        f16x8 a = *(const f16x8*)&lds[arow * ldr + kk * 32 + kofs];
        #pragma unroll
        for (int ct = 0; ct < CT; ct++) {
            f16x8 b = wp[(kk * CT + ct) * 64 + lane];
            acc[ct] = mfma16(a, b, acc[ct]);
        }
    }
}

template<int CT>
__device__ __forceinline__ void zacc(f32x4 acc[CT])
{
    #pragma unroll
    for (int ct = 0; ct < CT; ct++) acc[ct] = f32x4{0.f, 0.f, 0.f, 0.f};
}

// C/D layout (m89): col = lane&15, row = (lane>>4)*4 + reg
template<int CT, bool RELU>
__device__ __forceinline__ void store_f32(float* __restrict__ dst, int OUTC, int nbase,
                                          const float* __restrict__ bias, f32x4 acc[CT])
{
    const int lane = threadIdx.x & 63;
    const int wrow = (threadIdx.x >> 6) * 16;
    #pragma unroll
    for (int ct = 0; ct < CT; ct++) {
        int c = ct * 16 + (lane & 15);
        float bv = bias[c];
        #pragma unroll
        for (int r = 0; r < 4; r++) {
            int node = nbase + wrow + ((lane >> 4) << 2) + r;
            if (node < NN) {
                float v = acc[ct][r] + bv;
                if (RELU) v = frelu(v);
                dst[(size_t)node * OUTC + c] = v;
            }
        }
    }
}

template<int CT, bool RELU>
__device__ __forceinline__ void store_f16g(f16* __restrict__ dst, int OUTC, int nbase,
                                           const float* __restrict__ bias, f32x4 acc[CT])
{
    const int lane = threadIdx.x & 63;
    const int wrow = (threadIdx.x >> 6) * 16;
    #pragma unroll
    for (int ct = 0; ct < CT; ct++) {
        int c = ct * 16 + (lane & 15);
        float bv = bias[c];
        #pragma unroll
        for (int r = 0; r < 4; r++) {
            int node = nbase + wrow + ((lane >> 4) << 2) + r;
            if (node < NN) {
                float v = acc[ct][r] + bv;
                if (RELU) v = frelu(v);
                dst[(size_t)node * OUTC + c] = (f16)v;
            }
        }
    }
}

template<int CT>
__device__ __forceinline__ void store_lds_f16(f16* lds, int ldr,
                                              const float* __restrict__ bias, f32x4 acc[CT])
{
    const int lane = threadIdx.x & 63;
    const int wrow = (threadIdx.x >> 6) * 16;
    #pragma unroll
    for (int ct = 0; ct < CT; ct++) {
        int c = ct * 16 + (lane & 15);
        float bv = bias[c];
        #pragma unroll
        for (int r = 0; r < 4; r++) {
            int row = wrow + ((lane >> 4) << 2) + r;
            lds[row * ldr + c] = (f16)frelu(acc[ct][r] + bv);
        }
    }
}

// ---------------------------------------------------------------------------
// Encoder: h = relu(relu(x@W1+b1)@W2+b2) -> fp16 h.
// ---------------------------------------------------------------------------
__global__ __launch_bounds__(256) void enc_mfma(const float* __restrict__ x,
                                                const f16x8* __restrict__ wp1,
                                                const f16x8* __restrict__ wp2,
                                                const float* __restrict__ b1,
                                                const float* __restrict__ b2,
                                                f16* __restrict__ out)
{
    __shared__ __align__(16) f16 xs[64 * 264];
    __shared__ __align__(16) f16 h1[64 * 136];
    const int nbase = blockIdx.x * 64;
    stage_tile<256>(x, nbase, xs, 264, 0);
    __syncthreads();
    f32x4 acc[8];
    zacc<8>(acc);
    wave_gemm<256, 8>(xs, 264, wp1, acc);
    store_lds_f16<8>(h1, 136, b1, acc);
    __syncthreads();
    zacc<8>(acc);
    wave_gemm<128, 8>(h1, 136, wp2, acc);
    store_f16g<8, true>(out, 128, nbase, b2, acc);
}

// ---------------------------------------------------------------------------
// GraphConv combine: out = relu([agg|h] @ [Wrel;Wroot] + brel), fp16 in/out.
// ---------------------------------------------------------------------------
__global__ __launch_bounds__(256) void conv_mfma(const f16* __restrict__ agg,
                                                 const f16* __restrict__ h,
                                                 const f16x8* __restrict__ wp,
                                                 const float* __restrict__ brel,
                                                 f16* __restrict__ out)
{
    __shared__ __align__(16) f16 as_[64 * 264];
    const int nbase = blockIdx.x * 64;
    stage_tile_f16<128>(agg, nbase, as_, 264, 0);
    stage_tile_f16<128>(h,   nbase, as_, 264, 128);
    __syncthreads();
    f32x4 acc[8];
    zacc<8>(acc);
    wave_gemm<256, 8>(as_, 264, wp, acc);
    store_f16g<8, true>(out, 128, nbase, brel, acc);
}

// ---------------------------------------------------------------------------
// Heads (f32 math, f16 h input): mu/logvar. 32 nodes/block, 128 threads.
// ---------------------------------------------------------------------------
__global__ __launch_bounds__(128) void heads_kernel(const f16* __restrict__ h,
                                                    const float* __restrict__ Wmu, const float* __restrict__ bmu,
                                                    const float* __restrict__ Wlv, const float* __restrict__ blv,
                                                    float* __restrict__ out)
{
    __shared__ __align__(16) float hs[32 * 128];
    const int t = threadIdx.x;
    const int nbase = blockIdx.x * 32;
    #pragma unroll
    for (int i = 0; i < 8; i++) {
        int elem = t + i * 128;
        int row = elem >> 5;
        int c4  = elem & 31;
        union { f16 h[4]; uint2 u; } cv;
        cv.u = *(const uint2*)(h + (size_t)(nbase + row) * 128 + c4 * 4);
        float4 v = make_float4((float)cv.h[0], (float)cv.h[1], (float)cv.h[2], (float)cv.h[3]);
        *(float4*)&hs[row * 128 + c4 * 4] = v;
    }
    __syncthreads();
    const int c0 = (t & 15) * 4;
    const int n0 = (t >> 4) * 4;
    const bool is_mu = (c0 < 32);
    const float* W = is_mu ? Wmu : Wlv;
    const float* b = is_mu ? bmu : blv;
    const int cc = c0 & 31;
    float acc[4][4];
    #pragma unroll
    for (int n = 0; n < 4; n++)
        #pragma unroll
        for (int j = 0; j < 4; j++) acc[n][j] = 0.f;
    for (int k = 0; k < 128; k += 4) {
        float4 w0 = *(const float4*)(W + (size_t)(k + 0) * 32 + cc);
        float4 w1 = *(const float4*)(W + (size_t)(k + 1) * 32 + cc);
        float4 w2 = *(const float4*)(W + (size_t)(k + 2) * 32 + cc);
        float4 w3 = *(const float4*)(W + (size_t)(k + 3) * 32 + cc);
        #pragma unroll
        for (int n = 0; n < 4; n++) {
            float4 xv = *(const float4*)(&hs[(n0 + n) * 128 + k]);
            acc[n][0] += xv.x * w0.x + xv.y * w1.x + xv.z * w2.x + xv.w * w3.x;
            acc[n][1] += xv.x * w0.y + xv.y * w1.y + xv.z * w2.y + xv.w * w3.y;
            acc[n][2] += xv.x * w0.z + xv.y * w1.z + xv.z * w2.z + xv.w * w3.z;
            acc[n][3] += xv.x * w0.w + xv.y * w1.w + xv.z * w2.w + xv.w * w3.w;
        }
    }
    float4 bv = *(const float4*)(b + cc);
    float* base = out + (is_mu ? (size_t)25600000 : (size_t)28800000);
    #pragma unroll
    for (int n = 0; n < 4; n++) {
        float4 r;
        r.x = acc[n][0] + bv.x;
        r.y = acc[n][1] + bv.y;
        r.z = acc[n][2] + bv.z;
        r.w = acc[n][3] + bv.w;
        *(float4*)(base + (size_t)(nbase + n0 + n) * 32 + cc) = r;
    }
}

// z = mu + eps * exp(0.5*logvar)
__global__ __launch_bounds__(256) void reparam_kernel(const float* __restrict__ eps,
                                                      float* __restrict__ out)
{
    int i = blockIdx.x * 256 + threadIdx.x;
    float mu = out[25600000 + i];
    float lv = out[28800000 + i];
    out[32000000 + i] = fmaf(eps[i], expf(0.5f * lv), mu);
}

// ---------------------------------------------------------------------------
// Decoder: x_recon = relu(z@Wd1+bd1)@Wd2 + bd2, two fused MFMA layers, f32 out.
// ---------------------------------------------------------------------------
__global__ __launch_bounds__(256) void dec_mfma(const float* __restrict__ z,
                                                const f16x8* __restrict__ wp1,
                                                const float* __restrict__ bd1,
                                                const f16x8* __restrict__ wp2,
                                                const float* __restrict__ bd2,
                                                float* __restrict__ out)
{
    __shared__ __align__(16) f16 zs[64 * 40];
    __shared__ __align__(16) f16 hd[64 * 136];
    const int nbase = blockIdx.x * 64;
    stage_tile<32>(z, nbase, zs, 40, 0);
    __syncthreads();
    f32x4 acc[8];
    zacc<8>(acc);
    wave_gemm<32, 8>(zs, 40, wp1, acc);
    store_lds_f16<8>(hd, 136, bd1, acc);
    __syncthreads();
    f32x4 acc2[16];
    zacc<16>(acc2);
    wave_gemm<128, 16>(hd, 136, wp2, acc2);
    store_f32<16, false>(out, 256, nbase, bd2, acc2);
}

// ---------------------------------------------------------------------------
extern "C" void kernel_launch(void* const* d_in, const int* in_sizes, int n_in,
                              void* d_out, int out_size, void* d_ws, size_t ws_size,
                              hipStream_t stream)
{
    const float* x     = (const float*)d_in[0];
    const int*   ei    = (const int*)d_in[1];
    const float* ea    = (const float*)d_in[2];
    const float* W1    = (const float*)d_in[3];
    const float* b1    = (const float*)d_in[4];
    const float* W2    = (const float*)d_in[5];
    const float* b2    = (const float*)d_in[6];
    const float* Wrel1 = (const float*)d_in[7];
    const float* brel1 = (const float*)d_in[8];
    const float* Wroot1= (const float*)d_in[9];
    const float* Wrel2 = (const float*)d_in[10];
    const float* brel2 = (const float*)d_in[11];
    const float* Wroot2= (const float*)d_in[12];
    const float* Wmu   = (const float*)d_in[13];
    const float* bmu   = (const float*)d_in[14];
    const float* Wlv   = (const float*)d_in[15];
    const float* blv   = (const float*)d_in[16];
    const float* Wd1   = (const float*)d_in[17];
    const float* bd1   = (const float*)d_in[18];
    const float* Wd2   = (const float*)d_in[19];
    const float* bd2   = (const float*)d_in[20];
    const float* eps   = (const float*)d_in[21];
    float* out = (float*)d_out;

    // d_out region map (floats), all dead until later stages:
    //  [0, 6.4M)      B0 [N,128] f16      (25.6 MB)
    //  [6.4M, 12.8M)  B1 [N,128] f16      (25.6 MB)
    //  [12.8M, 16.1M) tmp_pairs int2[8*SEG] (13.1 MB)   CSR-build scratch
    //  [16.1M, 17.8M) tmp_dst  int[8*SEG]   (6.6 MB)    CSR-build scratch
    //  [25.6M, ...)   mu / logvar / z     (written by heads/reparam)
    //  x_recon [0, 25.6M) written last by dec_mfma.
    f16* B0 = (f16*)out;
    f16* B1 = B0 + 12800000;
    int2* tmp_pairs = (int2*)(out + 12800000);
    int*  tmp_dst   = (int*) (out + 16100000);

    char* ws = (char*)d_ws;
    int*   counts  = (int*)  (ws);                 // [N]      400000 B
    int*   cursor  = (int*)  (ws + 400000);        // [8]      32 B
    int*   offsets = (int*)  (ws + 400128);        // [N]      400000 B
    int*   bsums   = (int*)  (ws + 800128);        // [98]
    int2*  pairs   = (int2*) (ws + 801152);        // [E]      12.8 MB
    f16*   pack    = (f16*)  (ws + 13601152);      // 151552 halves

    const f16x8* wp_enc1  = (const f16x8*)(pack);
    const f16x8* wp_enc2  = (const f16x8*)(pack + 32768);
    const f16x8* wp_conv1 = (const f16x8*)(pack + 49152);
    const f16x8* wp_conv2 = (const f16x8*)(pack + 81920);
    const f16x8* wp_dec1  = (const f16x8*)(pack + 114688);
    const f16x8* wp_dec2  = (const f16x8*)(pack + 118784);

    const int* src = ei;          // edge_index row 0
    const int* dst = ei + EE;     // edge_index row 1

    // --- weight packing + CSR build (two-pass partition) ---
    prep_pack<<<592, 256, 0, stream>>>(W1, W2, Wrel1, Wroot1, Wrel2, Wroot2, Wd1, Wd2, pack);
    hipMemsetAsync(counts, 0, 400032, stream);     // counts + cursor
    partition_edges<<<250, 256, 0, stream>>>(src, dst, ea, cursor, tmp_pairs, tmp_dst);
    count_part<<<512, 256, 0, stream>>>(tmp_dst, cursor, counts);
    scan_blocks<<<98, 256, 0, stream>>>(counts, offsets, bsums);
    scan_sums<<<1, 128, 0, stream>>>(bsums);
    scan_add<<<98, 256, 0, stream>>>(offsets, bsums);
    fill_from_parts<<<512, 256, 0, stream>>>(tmp_pairs, tmp_dst, cursor, offsets, pairs);

    // --- forward pass ---
    enc_mfma<<<1563, 256, 0, stream>>>(x, wp_enc1, wp_enc2, b1, b2, B0);
    agg_q<<<6250, 256, 0, stream>>>(B0, pairs, offsets, counts, B1);
    conv_mfma<<<1563, 256, 0, stream>>>(B1, B0, wp_conv1, brel1, B1);
    agg_q<<<6250, 256, 0, stream>>>(B1, pairs, offsets, counts, B0);
    conv_mfma<<<1563, 256, 0, stream>>>(B0, B1, wp_conv2, brel2, B0);
    heads_kernel<<<3125, 128, 0, stream>>>(B0, Wmu, bmu, Wlv, blv, out);
    reparam_kernel<<<12500, 256, 0, stream>>>(eps, out);
    dec_mfma<<<1563, 256, 0, stream>>>(out + 32000000, wp_dec1, bd1, wp_dec2, bd2, out);
}

// Round 8
// 495.374 us; speedup vs baseline: 1.0458x; 1.0458x over previous
//
#include <hip/hip_runtime.h>
#include <math.h>

#define NN 100000
#define EE 1600000

typedef _Float16 f16;
typedef __attribute__((ext_vector_type(2))) _Float16 f16x2;
typedef __attribute__((ext_vector_type(8))) _Float16 f16x8;
typedef __attribute__((ext_vector_type(4))) float f32x4;
typedef unsigned int u32;

__device__ __forceinline__ float frelu(float v){ return v > 0.f ? v : 0.f; }

__device__ __forceinline__ f32x4 mfma16(f16x8 a, f16x8 b, f32x4 c){
    return __builtin_amdgcn_mfma_f32_16x16x32_f16(a, b, c, 0, 0, 0);
}

// ---------------------------------------------------------------------------
// Fused: count_deg (blocks 0..6249) || prep_pack (blocks 6250..6841).
// Independent work, both LDS-free -> one dispatch instead of two.
// ---------------------------------------------------------------------------
__global__ __launch_bounds__(256) void pack_count(const int* __restrict__ dst,
                                                  int* __restrict__ counts,
                                                  const float* __restrict__ W1,
                                                  const float* __restrict__ W2,
                                                  const float* __restrict__ Wrel1,
                                                  const float* __restrict__ Wroot1,
                                                  const float* __restrict__ Wrel2,
                                                  const float* __restrict__ Wroot2,
                                                  const float* __restrict__ Wd1,
                                                  const float* __restrict__ Wd2,
                                                  f16* __restrict__ pack)
{
    if (blockIdx.x < 6250) {                  // count_deg: 6250*256 = EE exact
        int e = blockIdx.x * 256 + threadIdx.x;
        atomicAdd(&counts[dst[e]], 1);
        return;
    }
    int t = (blockIdx.x - 6250) * 256 + threadIdx.x;   // 592*256 = 151552 exact
    float v;
    if (t < 32768) {                          // enc1: W1 [256,128], CT=8
        int l = t;
        int j = l & 7, lane = (l >> 3) & 63, ct = (l >> 9) & 7, kk = l >> 12;
        int k = kk * 32 + ((lane >> 4) << 3) + j, c = (ct << 4) + (lane & 15);
        v = W1[k * 128 + c];
    } else if (t < 49152) {                   // enc2: W2 [128,128], CT=8
        int l = t - 32768;
        int j = l & 7, lane = (l >> 3) & 63, ct = (l >> 9) & 7, kk = l >> 12;
        int k = kk * 32 + ((lane >> 4) << 3) + j, c = (ct << 4) + (lane & 15);
        v = W2[k * 128 + c];
    } else if (t < 81920) {                   // conv1: [Wrel1;Wroot1] K=256, CT=8
        int l = t - 49152;
        int j = l & 7, lane = (l >> 3) & 63, ct = (l >> 9) & 7, kk = l >> 12;
        int k = kk * 32 + ((lane >> 4) << 3) + j, c = (ct << 4) + (lane & 15);
        v = (k < 128) ? Wrel1[k * 128 + c] : Wroot1[(k - 128) * 128 + c];
    } else if (t < 114688) {                  // conv2
        int l = t - 81920;
        int j = l & 7, lane = (l >> 3) & 63, ct = (l >> 9) & 7, kk = l >> 12;
        int k = kk * 32 + ((lane >> 4) << 3) + j, c = (ct << 4) + (lane & 15);
        v = (k < 128) ? Wrel2[k * 128 + c] : Wroot2[(k - 128) * 128 + c];
    } else if (t < 118784) {                  // dec1: Wd1 [32,128], CT=8, kk=0
        int l = t - 114688;
        int j = l & 7, lane = (l >> 3) & 63, ct = (l >> 9) & 7;
        int k = ((lane >> 4) << 3) + j, c = (ct << 4) + (lane & 15);
        v = Wd1[k * 128 + c];
    } else {                                  // dec2: Wd2 [128,256], CT=16
        int l = t - 118784;
        int j = l & 7, lane = (l >> 3) & 63, ct = (l >> 9) & 15, kk = l >> 13;
        int k = kk * 32 + ((lane >> 4) << 3) + j, c = (ct << 4) + (lane & 15);
        v = Wd2[k * 256 + c];
    }
    pack[t] = (f16)v;
}

__global__ __launch_bounds__(256) void scan_blocks(const int* __restrict__ counts,
                                                   int* __restrict__ offsets,
                                                   int* __restrict__ bsums)
{
    __shared__ int lds[256];
    const int t = threadIdx.x, b = blockIdx.x;
    const int base = b * 1024 + t * 4;
    int v[4];
    #pragma unroll
    for (int i = 0; i < 4; i++) { int idx = base + i; v[i] = (idx < NN) ? counts[idx] : 0; }
    int s = v[0] + v[1] + v[2] + v[3];
    lds[t] = s;
    __syncthreads();
    for (int off = 1; off < 256; off <<= 1) {
        int y = (t >= off) ? lds[t - off] : 0;
        __syncthreads();
        lds[t] += y;
        __syncthreads();
    }
    int run = (t > 0) ? lds[t - 1] : 0;
    if (t == 255) bsums[b] = lds[255];
    #pragma unroll
    for (int i = 0; i < 4; i++) { int idx = base + i; if (idx < NN) offsets[idx] = run; run += v[i]; }
}

// Adds sum(bsums[0..b-1]) (raw block totals -- no separate scan pass needed).
__global__ __launch_bounds__(256) void scan_add_raw(int* __restrict__ offsets,
                                                    const int* __restrict__ bsums)
{
    __shared__ int red[256];
    const int b = blockIdx.x, t = threadIdx.x;
    red[t] = (t < b) ? bsums[t] : 0;          // b <= 97 < 98 entries
    __syncthreads();
    #pragma unroll
    for (int off = 128; off >= 1; off >>= 1) {
        if (t < off) red[t] += red[t + off];
        __syncthreads();
    }
    const int add = red[0];
    const int base = b * 1024 + t * 4;
    #pragma unroll
    for (int i = 0; i < 4; i++) { int idx = base + i; if (idx < NN) offsets[idx] += add; }
}

// ---------------------------------------------------------------------------
// Bucket fill, 4 dst-ranges (R6 scheme, fewer passes). Each range's pairs
// window (3.2MB) + offsets window (100KB) stay L2-resident on the 2 XCDs
// that own part = blockIdx&3 under round-robin dispatch -> write-combining
// and local atomics; edge-array re-reads are 4x (L3-served), half of R6's 8x.
// ---------------------------------------------------------------------------
__global__ __launch_bounds__(256) void fill_csr_part4(const int* __restrict__ src,
                                                      const int* __restrict__ dst,
                                                      const float* __restrict__ ea,
                                                      int* __restrict__ offsets,
                                                      int2* __restrict__ pairs)
{
    const int part = blockIdx.x & 3;
    const int cb   = blockIdx.x >> 2;          // 0..511
    const int lo   = part * 25000, hi = lo + 25000;
    const int ebase = cb * 3125;               // 512*3125 = EE exact
    for (int e = ebase + threadIdx.x; e < ebase + 3125; e += 256) {
        int d = dst[e];
        if (d >= lo && d < hi) {
            int p = atomicAdd(&offsets[d], 1);
            pairs[p] = make_int2(src[e], __float_as_int(ea[e]));
        }
    }
}

// ---------------------------------------------------------------------------
// Aggregation: quarter-wave (16 lanes x 16B) per node. 4 nodes per wave,
// 1KB of gather data in flight per wave-instruction, v_fma_mix accumulate.
// ---------------------------------------------------------------------------
__global__ __launch_bounds__(256) void agg_q(const f16* __restrict__ h,
                                             const int2* __restrict__ pairs,
                                             const int* __restrict__ offsets,
                                             const int* __restrict__ counts,
                                             f16* __restrict__ out)
{
    const int gt   = blockIdx.x * 256 + threadIdx.x;   // grid exact: 6250*256
    const int node = gt >> 4;                          // 100000 nodes
    const int ch   = gt & 15;                          // 16B chunk within row
    const int end  = offsets[node];
    int i = end - counts[node];
    float acc[8];
    #pragma unroll
    for (int j = 0; j < 8; j++) acc[j] = 0.f;
    const uint4* __restrict__ h16 = (const uint4*)h;   // 16 chunks per row
    for (; i + 2 <= end; i += 2) {
        int2 p0 = pairs[i], p1 = pairs[i + 1];
        uint4 r0 = h16[(size_t)p0.x * 16 + ch];
        uint4 r1 = h16[(size_t)p1.x * 16 + ch];
        float w0 = __int_as_float(p0.y), w1 = __int_as_float(p1.y);
        const f16* e0 = (const f16*)&r0;
        const f16* e1 = (const f16*)&r1;
        #pragma unroll
        for (int j = 0; j < 8; j++) acc[j] = fmaf(w0, (float)e0[j], acc[j]);
        #pragma unroll
        for (int j = 0; j < 8; j++) acc[j] = fmaf(w1, (float)e1[j], acc[j]);
    }
    if (i < end) {
        int2 p0 = pairs[i];
        uint4 r0 = h16[(size_t)p0.x * 16 + ch];
        float w0 = __int_as_float(p0.y);
        const f16* e0 = (const f16*)&r0;
        #pragma unroll
        for (int j = 0; j < 8; j++) acc[j] = fmaf(w0, (float)e0[j], acc[j]);
    }
    union { f16 hh[8]; uint4 u; } cv;
    #pragma unroll
    for (int j = 0; j < 8; j++) cv.hh[j] = (f16)acc[j];
    ((uint4*)out)[(size_t)node * 16 + ch] = cv.u;
}

// ---------------------------------------------------------------------------
// MFMA GEMM building blocks. 64 nodes/block, 4 waves, wave = 16 nodes.
// ---------------------------------------------------------------------------
template<int C>
__device__ __forceinline__ void stage_tile(const float* __restrict__ src, int nbase,
                                           f16* lds, int ldr, int colofs)
{
    const int t = threadIdx.x;
    #pragma unroll
    for (int i = 0; i < (64 * C / 4) / 256; i++) {
        int elem = t + i * 256;
        int row = elem / (C / 4);
        int c4  = elem % (C / 4);
        int srow = nbase + row; if (srow >= NN) srow = NN - 1;
        float4 v = *(const float4*)(src + (size_t)srow * C + c4 * 4);
        union { f16 h[4]; uint2 u; } cv;
        cv.h[0] = (f16)v.x; cv.h[1] = (f16)v.y; cv.h[2] = (f16)v.z; cv.h[3] = (f16)v.w;
        *(uint2*)&lds[row * ldr + colofs + c4 * 4] = cv.u;
    }
}

template<int C>
__device__ __forceinline__ void stage_tile_f16(const f16* __restrict__ src, int nbase,
                                               f16* lds, int ldr, int colofs)
{
    const int t = threadIdx.x;
    #pragma unroll
    for (int i = 0; i < (64 * C / 4) / 256; i++) {
        int elem = t + i * 256;
        int row = elem / (C / 4);
        int c4  = elem % (C / 4);
        int srow = nbase + row; if (srow >= NN) srow = NN - 1;
        uint2 v = *(const uint2*)(src + (size_t)srow * C + c4 * 4);
        *(uint2*)&lds[row * ldr + colofs + c4 * 4] = v;
    }
}

template<int K, int CT>
__device__ __forceinline__ void wave_gemm(const f16* lds, int ldr,
                                          const f16x8* __restrict__ wp, f32x4 acc[CT])
{
    const int lane = threadIdx.x & 63;
    const int wrow = (threadIdx.x >> 6) * 16;
    const int arow = wrow + (lane & 15);
    const int kofs = (lane >> 4) << 3;
    #pragma unroll
    for (int kk = 0; kk < K / 32; kk++) {
        f16x8 a = *(const f16x8*)&lds[arow * ldr + kk * 32 + kofs];
        #pragma unroll
        for (int ct = 0; ct < CT; ct++) {
            f16x8 b = wp[(kk * CT + ct) * 64 + lane];
            acc[ct] = mfma16(a, b, acc[ct]);
        }
    }
}

template<int CT>
__device__ __forceinline__ void zacc(f32x4 acc[CT])
{
    #pragma unroll
    for (int ct = 0; ct < CT; ct++) acc[ct] = f32x4{0.f, 0.f, 0.f, 0.f};
}

// C/D layout (m89): col = lane&15, row = (lane>>4)*4 + reg
template<int CT, bool RELU>
__device__ __forceinline__ void store_f32(float* __restrict__ dst, int OUTC, int nbase,
                                          const float* __restrict__ bias, f32x4 acc[CT])
{
    const int lane = threadIdx.x & 63;
    const int wrow = (threadIdx.x >> 6) * 16;
    #pragma unroll
    for (int ct = 0; ct < CT; ct++) {
        int c = ct * 16 + (lane & 15);
        float bv = bias[c];
        #pragma unroll
        for (int r = 0; r < 4; r++) {
            int node = nbase + wrow + ((lane >> 4) << 2) + r;
            if (node < NN) {
                float v = acc[ct][r] + bv;
                if (RELU) v = frelu(v);
                dst[(size_t)node * OUTC + c] = v;
            }
        }
    }
}

template<int CT, bool RELU>
__device__ __forceinline__ void store_f16g(f16* __restrict__ dst, int OUTC, int nbase,
                                           const float* __restrict__ bias, f32x4 acc[CT])
{
    const int lane = threadIdx.x & 63;
    const int wrow = (threadIdx.x >> 6) * 16;
    #pragma unroll
    for (int ct = 0; ct < CT; ct++) {
        int c = ct * 16 + (lane & 15);
        float bv = bias[c];
        #pragma unroll
        for (int r = 0; r < 4; r++) {
            int node = nbase + wrow + ((lane >> 4) << 2) + r;
            if (node < NN) {
                float v = acc[ct][r] + bv;
                if (RELU) v = frelu(v);
                dst[(size_t)node * OUTC + c] = (f16)v;
            }
        }
    }
}

template<int CT>
__device__ __forceinline__ void store_lds_f16(f16* lds, int ldr,
                                              const float* __restrict__ bias, f32x4 acc[CT])
{
    const int lane = threadIdx.x & 63;
    const int wrow = (threadIdx.x >> 6) * 16;
    #pragma unroll
    for (int ct = 0; ct < CT; ct++) {
        int c = ct * 16 + (lane & 15);
        float bv = bias[c];
        #pragma unroll
        for (int r = 0; r < 4; r++) {
            int row = wrow + ((lane >> 4) << 2) + r;
            lds[row * ldr + c] = (f16)frelu(acc[ct][r] + bv);
        }
    }
}

// ---------------------------------------------------------------------------
// Encoder: h = relu(relu(x@W1+b1)@W2+b2) -> fp16 h.
// ---------------------------------------------------------------------------
__global__ __launch_bounds__(256) void enc_mfma(const float* __restrict__ x,
                                                const f16x8* __restrict__ wp1,
                                                const f16x8* __restrict__ wp2,
                                                const float* __restrict__ b1,
                                                const float* __restrict__ b2,
                                                f16* __restrict__ out)
{
    __shared__ __align__(16) f16 xs[64 * 264];
    __shared__ __align__(16) f16 h1[64 * 136];
    const int nbase = blockIdx.x * 64;
    stage_tile<256>(x, nbase, xs, 264, 0);
    __syncthreads();
    f32x4 acc[8];
    zacc<8>(acc);
    wave_gemm<256, 8>(xs, 264, wp1, acc);
    store_lds_f16<8>(h1, 136, b1, acc);
    __syncthreads();
    zacc<8>(acc);
    wave_gemm<128, 8>(h1, 136, wp2, acc);
    store_f16g<8, true>(out, 128, nbase, b2, acc);
}

// ---------------------------------------------------------------------------
// GraphConv combine: out = relu([agg|h] @ [Wrel;Wroot] + brel), fp16 in/out.
// ---------------------------------------------------------------------------
__global__ __launch_bounds__(256) void conv_mfma(const f16* __restrict__ agg,
                                                 const f16* __restrict__ h,
                                                 const f16x8* __restrict__ wp,
                                                 const float* __restrict__ brel,
                                                 f16* __restrict__ out)
{
    __shared__ __align__(16) f16 as_[64 * 264];
    const int nbase = blockIdx.x * 64;
    stage_tile_f16<128>(agg, nbase, as_, 264, 0);
    stage_tile_f16<128>(h,   nbase, as_, 264, 128);
    __syncthreads();
    f32x4 acc[8];
    zacc<8>(acc);
    wave_gemm<256, 8>(as_, 264, wp, acc);
    store_f16g<8, true>(out, 128, nbase, brel, acc);
}

// ---------------------------------------------------------------------------
// Heads + reparam fused: mu/logvar (f32 math) -> LDS -> z = mu+eps*exp(.5lv).
// 32 nodes/block, 128 threads. Saves one dispatch + the mu/lv/z re-reads.
// ---------------------------------------------------------------------------
__global__ __launch_bounds__(128) void heads_rp(const f16* __restrict__ h,
                                                const float* __restrict__ Wmu, const float* __restrict__ bmu,
                                                const float* __restrict__ Wlv, const float* __restrict__ blv,
                                                const float* __restrict__ eps,
                                                float* __restrict__ out)
{
    __shared__ __align__(16) float hs[32 * 128];
    __shared__ __align__(16) float muS[32 * 32];
    __shared__ __align__(16) float lvS[32 * 32];
    const int t = threadIdx.x;
    const int nbase = blockIdx.x * 32;
    #pragma unroll
    for (int i = 0; i < 8; i++) {
        int elem = t + i * 128;
        int row = elem >> 5;
        int c4  = elem & 31;
        union { f16 h[4]; uint2 u; } cv;
        cv.u = *(const uint2*)(h + (size_t)(nbase + row) * 128 + c4 * 4);
        float4 v = make_float4((float)cv.h[0], (float)cv.h[1], (float)cv.h[2], (float)cv.h[3]);
        *(float4*)&hs[row * 128 + c4 * 4] = v;
    }
    __syncthreads();
    const int c0 = (t & 15) * 4;
    const int n0 = (t >> 4) * 4;
    const bool is_mu = (c0 < 32);
    const float* W = is_mu ? Wmu : Wlv;
    const float* b = is_mu ? bmu : blv;
    const int cc = c0 & 31;
    float acc[4][4];
    #pragma unroll
    for (int n = 0; n < 4; n++)
        #pragma unroll
        for (int j = 0; j < 4; j++) acc[n][j] = 0.f;
    for (int k = 0; k < 128; k += 4) {
        float4 w0 = *(const float4*)(W + (size_t)(k + 0) * 32 + cc);
        float4 w1 = *(const float4*)(W + (size_t)(k + 1) * 32 + cc);
        float4 w2 = *(const float4*)(W + (size_t)(k + 2) * 32 + cc);
        float4 w3 = *(const float4*)(W + (size_t)(k + 3) * 32 + cc);
        #pragma unroll
        for (int n = 0; n < 4; n++) {
            float4 xv = *(const float4*)(&hs[(n0 + n) * 128 + k]);
            acc[n][0] += xv.x * w0.x + xv.y * w1.x + xv.z * w2.x + xv.w * w3.x;
            acc[n][1] += xv.x * w0.y + xv.y * w1.y + xv.z * w2.y + xv.w * w3.y;
            acc[n][2] += xv.x * w0.z + xv.y * w1.z + xv.z * w2.z + xv.w * w3.z;
            acc[n][3] += xv.x * w0.w + xv.y * w1.w + xv.z * w2.w + xv.w * w3.w;
        }
    }
    float4 bv = *(const float4*)(b + cc);
    float* gbase = out + (is_mu ? (size_t)25600000 : (size_t)28800000);
    float* sbase = is_mu ? muS : lvS;
    #pragma unroll
    for (int n = 0; n < 4; n++) {
        float4 r;
        r.x = acc[n][0] + bv.x;
        r.y = acc[n][1] + bv.y;
        r.z = acc[n][2] + bv.z;
        r.w = acc[n][3] + bv.w;
        *(float4*)(gbase + (size_t)(nbase + n0 + n) * 32 + cc) = r;
        *(float4*)(sbase + (n0 + n) * 32 + cc) = r;
    }
    __syncthreads();
    // reparam: 1024 elems, 8 per thread (two float4 groups)
    {
        const int node = t >> 2;             // 0..31
        const int ch0  = (t & 3) * 8;        // 0,8,16,24
        const size_t g = (size_t)(nbase + node) * 32 + ch0;
        float4 e0 = *(const float4*)(eps + g);
        float4 e1 = *(const float4*)(eps + g + 4);
        const float* mu = &muS[node * 32 + ch0];
        const float* lv = &lvS[node * 32 + ch0];
        float4 z0, z1;
        z0.x = fmaf(e0.x, expf(0.5f * lv[0]), mu[0]);
        z0.y = fmaf(e0.y, expf(0.5f * lv[1]), mu[1]);
        z0.z = fmaf(e0.z, expf(0.5f * lv[2]), mu[2]);
        z0.w = fmaf(e0.w, expf(0.5f * lv[3]), mu[3]);
        z1.x = fmaf(e1.x, expf(0.5f * lv[4]), mu[4]);
        z1.y = fmaf(e1.y, expf(0.5f * lv[5]), mu[5]);
        z1.z = fmaf(e1.z, expf(0.5f * lv[6]), mu[6]);
        z1.w = fmaf(e1.w, expf(0.5f * lv[7]), mu[7]);
        *(float4*)(out + 32000000 + g) = z0;
        *(float4*)(out + 32000000 + g + 4) = z1;
    }
}

// ---------------------------------------------------------------------------
// Decoder: x_recon = relu(z@Wd1+bd1)@Wd2 + bd2, two fused MFMA layers, f32 out.
// ---------------------------------------------------------------------------
__global__ __launch_bounds__(256) void dec_mfma(const float* __restrict__ z,
                                                const f16x8* __restrict__ wp1,
                                                const float* __restrict__ bd1,
                                                const f16x8* __restrict__ wp2,
                                                const float* __restrict__ bd2,
                                                float* __restrict__ out)
{
    __shared__ __align__(16) f16 zs[64 * 40];
    __shared__ __align__(16) f16 hd[64 * 136];
    const int nbase = blockIdx.x * 64;
    stage_tile<32>(z, nbase, zs, 40, 0);
    __syncthreads();
    f32x4 acc[8];
    zacc<8>(acc);
    wave_gemm<32, 8>(zs, 40, wp1, acc);
    store_lds_f16<8>(hd, 136, bd1, acc);
    __syncthreads();
    f32x4 acc2[16];
    zacc<16>(acc2);
    wave_gemm<128, 16>(hd, 136, wp2, acc2);
    store_f32<16, false>(out, 256, nbase, bd2, acc2);
}

// ---------------------------------------------------------------------------
extern "C" void kernel_launch(void* const* d_in, const int* in_sizes, int n_in,
                              void* d_out, int out_size, void* d_ws, size_t ws_size,
                              hipStream_t stream)
{
    const float* x     = (const float*)d_in[0];
    const int*   ei    = (const int*)d_in[1];
    const float* ea    = (const float*)d_in[2];
    const float* W1    = (const float*)d_in[3];
    const float* b1    = (const float*)d_in[4];
    const float* W2    = (const float*)d_in[5];
    const float* b2    = (const float*)d_in[6];
    const float* Wrel1 = (const float*)d_in[7];
    const float* brel1 = (const float*)d_in[8];
    const float* Wroot1= (const float*)d_in[9];
    const float* Wrel2 = (const float*)d_in[10];
    const float* brel2 = (const float*)d_in[11];
    const float* Wroot2= (const float*)d_in[12];
    const float* Wmu   = (const float*)d_in[13];
    const float* bmu   = (const float*)d_in[14];
    const float* Wlv   = (const float*)d_in[15];
    const float* blv   = (const float*)d_in[16];
    const float* Wd1   = (const float*)d_in[17];
    const float* bd1   = (const float*)d_in[18];
    const float* Wd2   = (const float*)d_in[19];
    const float* bd2   = (const float*)d_in[20];
    const float* eps   = (const float*)d_in[21];
    float* out = (float*)d_out;

    // fp16 h ping-pong buffers live in d_out's x_recon region (dead until dec).
    f16* B0 = (f16*)out;                // [N,128] f16 = 25.6 MB
    f16* B1 = B0 + 12800000;            // [N,128] f16

    char* ws = (char*)d_ws;
    int*   counts  = (int*)  (ws);                 // [N]      400 KB
    int*   offsets = (int*)  (ws + 400000);        // [N]      400 KB
    int*   bsums   = (int*)  (ws + 800000);        // [98]
    int2*  pairs   = (int2*) (ws + 801024);        // [E]      12.8 MB
    f16*   pack    = (f16*)  (ws + 13601024);      // 151552 halves

    const f16x8* wp_enc1  = (const f16x8*)(pack);
    const f16x8* wp_enc2  = (const f16x8*)(pack + 32768);
    const f16x8* wp_conv1 = (const f16x8*)(pack + 49152);
    const f16x8* wp_conv2 = (const f16x8*)(pack + 81920);
    const f16x8* wp_dec1  = (const f16x8*)(pack + 114688);
    const f16x8* wp_dec2  = (const f16x8*)(pack + 118784);

    const int* src = ei;          // edge_index row 0
    const int* dst = ei + EE;     // edge_index row 1

    // --- CSR build + weight packing (12 dispatches total incl. memset) ---
    hipMemsetAsync(counts, 0, NN * sizeof(int), stream);
    pack_count<<<6842, 256, 0, stream>>>(dst, counts, W1, W2, Wrel1, Wroot1,
                                         Wrel2, Wroot2, Wd1, Wd2, pack);
    scan_blocks<<<98, 256, 0, stream>>>(counts, offsets, bsums);
    scan_add_raw<<<98, 256, 0, stream>>>(offsets, bsums);
    fill_csr_part4<<<2048, 256, 0, stream>>>(src, dst, ea, offsets, pairs);

    // --- forward pass ---
    enc_mfma<<<1563, 256, 0, stream>>>(x, wp_enc1, wp_enc2, b1, b2, B0);
    agg_q<<<6250, 256, 0, stream>>>(B0, pairs, offsets, counts, B1);
    conv_mfma<<<1563, 256, 0, stream>>>(B1, B0, wp_conv1, brel1, B1);
    agg_q<<<6250, 256, 0, stream>>>(B1, pairs, offsets, counts, B0);
    conv_mfma<<<1563, 256, 0, stream>>>(B0, B1, wp_conv2, brel2, B0);
    heads_rp<<<3125, 128, 0, stream>>>(B0, Wmu, bmu, Wlv, blv, eps, out);
    dec_mfma<<<1563, 256, 0, stream>>>(out + 32000000, wp_dec1, bd1, wp_dec2, bd2, out);
}